// Round 13
// baseline (262.199 us; speedup 1.0000x reference)
//
#include <hip/hip_runtime.h>
#include <math.h>

#define E 256
#define TD 128
#define FF 1024
#define NTOK 4096

typedef __attribute__((ext_vector_type(8))) __bf16 bf16x8;
typedef __attribute__((ext_vector_type(4))) float f32x4;

__device__ __forceinline__ unsigned short f2bf(float x) {
    __bf16 b = (__bf16)x;
    return __builtin_bit_cast(unsigned short, b);
}
__device__ __forceinline__ float bf2f(unsigned short h) {
    return __uint_as_float(((unsigned)h) << 16);
}
__device__ __forceinline__ float gelu_fast(float x) {
    float ex = __expf(-x * (1.5957691216057308f + 0.07135481627f * x * x));
    return x * __builtin_amdgcn_rcpf(1.f + ex);
}
// LDS-only barrier: waits ds ops, does NOT drain vmcnt (gll prefetches stay in flight)
__device__ __forceinline__ void bar_lds() {
    __builtin_amdgcn_sched_barrier(0);
    asm volatile("s_waitcnt lgkmcnt(0)" ::: "memory");
    __builtin_amdgcn_s_barrier();
    __builtin_amdgcn_sched_barrier(0);
}
// async global->LDS, 16B/lane: dest = uniform base + lane*16, src = per-lane
__device__ __forceinline__ void gll16(const unsigned short* g, unsigned short* l) {
    __builtin_amdgcn_global_load_lds(
        (const __attribute__((address_space(1))) unsigned int*)g,
        (__attribute__((address_space(3))) unsigned int*)l, 16, 0, 0);
}

#define WVM2 asm volatile("s_waitcnt vmcnt(2)" ::: "memory")
#define WVM1 asm volatile("s_waitcnt vmcnt(1)" ::: "memory")
#define WVM0 asm volatile("s_waitcnt vmcnt(0)" ::: "memory")
// depth-3 issuance with a 4-slot ring (round-12-proven): outstanding = {S,S+1,S+2};
// vmcnt(2) retires S. ISSUE(S+3) targets slot consumed at step S-1 (one-step margin).
#define WAITV(S) do { if ((S) <= 125) { WVM2; } else if ((S) == 126) { WVM1; } else { WVM0; } } while (0)

// ==================== PREP ==================== (identical to round 12)
__global__ __launch_bounds__(256) void prep_kernel(
    const float* __restrict__ W1, const float* __restrict__ W2, const float* __restrict__ b1,
    const float* __restrict__ tt, const float* __restrict__ bgt,
    const float* __restrict__ Wp, const float* __restrict__ bp,
    const float* __restrict__ g_tok, const float* __restrict__ b_tok,
    const float* __restrict__ g_img, const float* __restrict__ b_img,
    const float* __restrict__ Wq, const float* __restrict__ bq,
    const float* __restrict__ Wk, const float* __restrict__ bk,
    const float* __restrict__ Wv, const float* __restrict__ bv,
    const float* __restrict__ Wo,
    const float* __restrict__ g_ffn, const float* __restrict__ b_ffn,
    unsigned short* __restrict__ w1s, unsigned short* __restrict__ w2s,
    unsigned short* __restrict__ wks, unsigned short* __restrict__ wvs,
    float* __restrict__ Gk, float* __restrict__ sbk,
    float* __restrict__ G1, float* __restrict__ B1)
{
    const int t = threadIdx.x;
    const int lane = t & 63;
    if (blockIdx.x < 256) {
        int gid = blockIdx.x * 256 + t;
        if (gid < 32768) {
            int row = gid >> 5;
            int k0 = (gid & 31) * 8;
            f32x4 wa = *(const f32x4*)(W1 + row * 256 + k0);
            f32x4 wb = *(const f32x4*)(W1 + row * 256 + k0 + 4);
            f32x4 ga = *(const f32x4*)(g_ffn + k0);
            f32x4 gb = *(const f32x4*)(g_ffn + k0 + 4);
            ushort4 o0, o1;
            o0.x = f2bf(wa[0]*ga[0]); o0.y = f2bf(wa[1]*ga[1]);
            o0.z = f2bf(wa[2]*ga[2]); o0.w = f2bf(wa[3]*ga[3]);
            o1.x = f2bf(wb[0]*gb[0]); o1.y = f2bf(wb[1]*gb[1]);
            o1.z = f2bf(wb[2]*gb[2]); o1.w = f2bf(wb[3]*gb[3]);
            int dst = ((row >> 4) * 8 + (k0 >> 5)) * 512 + (((k0 >> 3) & 3) * 16 + (row & 15)) * 8;
            *(ushort4*)(w1s + dst) = o0;
            *(ushort4*)(w1s + dst + 4) = o1;
        } else {
            int g2 = gid - 32768;
            int o = g2 >> 7;
            int f0 = (g2 & 127) * 8;
            f32x4 wa = *(const f32x4*)(W2 + o * 1024 + f0);
            f32x4 wb = *(const f32x4*)(W2 + o * 1024 + f0 + 4);
            ushort4 o0, o1;
            o0.x = f2bf(wa[0]); o0.y = f2bf(wa[1]); o0.z = f2bf(wa[2]); o0.w = f2bf(wa[3]);
            o1.x = f2bf(wb[0]); o1.y = f2bf(wb[1]); o1.z = f2bf(wb[2]); o1.w = f2bf(wb[3]);
            int dst = (((f0 >> 8) * 16 + (o >> 4)) * 8 + ((f0 >> 5) & 7)) * 512
                    + (((f0 >> 3) & 3) * 16 + (o & 15)) * 8;
            *(ushort4*)(w2s + dst) = o0;
            *(ushort4*)(w2s + dst + 4) = o1;
        }
        if (gid < 1024) {
            int row = gid;
            float gacc = 0.f, bacc = 0.f;
            for (int k = 0; k < 256; k += 4) {
                f32x4 w = *(const f32x4*)(W1 + row * 256 + k);
                f32x4 g = *(const f32x4*)(g_ffn + k);
                f32x4 bb = *(const f32x4*)(b_ffn + k);
                gacc += w[0]*g[0] + w[1]*g[1] + w[2]*g[2] + w[3]*g[3];
                bacc += w[0]*bb[0] + w[1]*bb[1] + w[2]*bb[2] + w[3]*bb[3];
            }
            G1[row] = gacc;
            B1[row] = bacc + b1[row];
        }
        return;
    }
    const int bi = blockIdx.x - 256;
    __shared__ float tokL[2][TD];
    __shared__ float kvn[2][E];
    __shared__ float ks[2][E];
    __shared__ float vs[2][E];
    __shared__ float red[8];
    __shared__ float redk[16][4], redb[16][4];

    if (t < TD) tokL[0][t] = tt[bi * TD + t];
    else tokL[1][t - TD] = bgt[bi * TD + (t - TD)];
    __syncthreads();

    {
        float a0 = bp[t], a1 = a0;
        const float* wr = Wp + (size_t)t * TD;
        for (int i = 0; i < TD; i += 4) {
            f32x4 w = *(const f32x4*)(wr + i);
            f32x4 x0 = *(const f32x4*)(&tokL[0][i]);
            f32x4 x1 = *(const f32x4*)(&tokL[1][i]);
            a0 += w[0]*x0[0] + w[1]*x0[1] + w[2]*x0[2] + w[3]*x0[3];
            a1 += w[0]*x1[0] + w[1]*x1[1] + w[2]*x1[2] + w[3]*x1[3];
        }
        kvn[0][t] = a0; kvn[1][t] = a1;
    }
    __syncthreads();
    for (int j = 0; j < 2; ++j) {
        float v = kvn[j][t];
        float s = v, s2 = v * v;
        for (int off = 32; off; off >>= 1) { s += __shfl_down(s, off); s2 += __shfl_down(s2, off); }
        if (lane == 0) { red[t >> 6] = s; red[4 + (t >> 6)] = s2; }
        __syncthreads();
        float S = red[0] + red[1] + red[2] + red[3];
        float S2 = red[4] + red[5] + red[6] + red[7];
        float m = S * (1.f / E);
        float rs = rsqrtf(S2 * (1.f / E) - m * m + 1e-5f);
        __syncthreads();
        kvn[j][t] = (v - m) * rs * g_tok[t] + b_tok[t];
    }
    __syncthreads();
    {
        float k0 = bk[t], k1 = k0, v0 = bv[t], v1 = v0;
        const float* wkr = Wk + (size_t)t * E;
        const float* wvr = Wv + (size_t)t * E;
        for (int i = 0; i < E; i += 4) {
            f32x4 wk4 = *(const f32x4*)(wkr + i);
            f32x4 wv4 = *(const f32x4*)(wvr + i);
            f32x4 x0 = *(const f32x4*)(&kvn[0][i]);
            f32x4 x1 = *(const f32x4*)(&kvn[1][i]);
            k0 += wk4[0]*x0[0] + wk4[1]*x0[1] + wk4[2]*x0[2] + wk4[3]*x0[3];
            k1 += wk4[0]*x1[0] + wk4[1]*x1[1] + wk4[2]*x1[2] + wk4[3]*x1[3];
            v0 += wv4[0]*x0[0] + wv4[1]*x0[1] + wv4[2]*x0[2] + wv4[3]*x0[3];
            v1 += wv4[0]*x1[0] + wv4[1]*x1[1] + wv4[2]*x1[2] + wv4[3]*x1[3];
        }
        ks[0][t] = k0; ks[1][t] = k1; vs[0][t] = v0; vs[1][t] = v1;
    }
    __syncthreads();
    const float inv = 0.17677669529663687f;
    const float gi = g_img[t], bimg = b_img[t];
    for (int c = 0; c < 16; ++c) {
        int j = c >> 3, h = c & 7;
        float awk = 0.f, awv = 0.f;
        const float* wqc = Wq + (size_t)(h * 32) * E + t;
        const float* wor = Wo + (size_t)t * E + h * 32;
        #pragma unroll
        for (int d = 0; d < 32; d += 4) {
            f32x4 kv = *(const f32x4*)(&ks[j][h * 32 + d]);
            f32x4 vv = *(const f32x4*)(&vs[j][h * 32 + d]);
            f32x4 wo4 = *(const f32x4*)(wor + d);
            awk += kv[0]*wqc[(size_t)(d+0)*E] + kv[1]*wqc[(size_t)(d+1)*E]
                 + kv[2]*wqc[(size_t)(d+2)*E] + kv[3]*wqc[(size_t)(d+3)*E];
            awv += wo4[0]*vv[0] + wo4[1]*vv[1] + wo4[2]*vv[2] + wo4[3]*vv[3];
        }
        float base = awk * inv;
        wks[(bi * 8 + (t >> 5)) * 512 + (((t >> 3) & 3) * 16 + c) * 8 + (t & 7)] = f2bf(gi * base);
        wvs[(bi * 16 + (t >> 4)) * 512 + ((c >> 3) * 16 + (t & 15)) * 8 + (c & 7)] = f2bf(awv);
        float rk = gi * base, rb = bimg * base;
        for (int off = 32; off; off >>= 1) { rk += __shfl_down(rk, off); rb += __shfl_down(rb, off); }
        if (lane == 0) { redk[c][t >> 6] = rk; redb[c][t >> 6] = rb; }
    }
    #pragma unroll
    for (int c2 = 16; c2 < 32; ++c2)
        wvs[(bi * 16 + (t >> 4)) * 512 + ((c2 >> 3) * 16 + (t & 15)) * 8 + (c2 & 7)] = 0;
    __syncthreads();
    if (t < 16) {
        int c = t, j = c >> 3, h = c & 7;
        float s = 0.f;
        for (int d = 0; d < 32; ++d) s += bq[h * 32 + d] * ks[j][h * 32 + d];
        Gk[bi * 16 + c] = redk[c][0] + redk[c][1] + redk[c][2] + redk[c][3];
        sbk[bi * 16 + c] = redb[c][0] + redb[c][1] + redb[c][2] + redb[c][3] + s * inv;
    }
}

// ==================== FUSED MAIN ====================
// 128 rows/block, 1024 thr (16 waves), 1 blk/CU, LDS = 160 KiB exactly.
// Wave = (mh=wid>>3 row-half, cg=wid&7 col-group of 32). FFN inner loop identical
// to round 12 (4 m-tiles x 2 og, 4-slot depth-3 gll ring, counted vmcnt).
__global__ __launch_bounds__(1024, 4) void fused_main_kernel(
    const float* __restrict__ img,
    const float* __restrict__ pbo, const float* __restrict__ pb2,
    const unsigned short* __restrict__ w1s, const unsigned short* __restrict__ w2s,
    const unsigned short* __restrict__ wks, const unsigned short* __restrict__ wvs,
    const float* __restrict__ Gk, const float* __restrict__ sbk,
    const float* __restrict__ B1,
    float* __restrict__ out)
{
    __shared__ __align__(16) char smem[163840];
    unsigned short* xsf = (unsigned short*)smem;              // [128*256] bf16, swz (r&31)<<3 (64K)
    // ring @ 65536: 16 waves x 4 slots x 1KB = 64K
    unsigned short* hsf = (unsigned short*)(smem + 131072);   // [128*128] bf16, swz (r&15)<<3 (32K)
    // attention-phase aliases inside ring region [65536,131072):
    float* part_s  = (float*)(smem + 65536);                  // [128*9]
    float* part_s2 = (float*)(smem + 70656);                  // [128*9]
    unsigned short* alf = (unsigned short*)(smem + 65536);    // [128*32] (after parts dead)
    float* scf     = (float*)(smem + 76800);                  // [2*128*16] (16K)
    float* outsf   = (float*)(smem + 65536);                  // [128*128] f32 epilogue (ring dead)
    // stats inside hsf region (dead before first hsf write):
    float* mean_s  = (float*)(smem + 131072);                 // [128]
    float* rstd_s  = (float*)(smem + 131584);                 // [128]

    const int t = threadIdx.x;
    const int lane = t & 63;
    const int wid = t >> 6;          // 0..15
    const int l15 = lane & 15;
    const int l4 = lane >> 4;
    const int bi = blockIdx.x >> 5;
    const int n0 = (blockIdx.x & 31) << 7;   // 32 tiles of 128 rows
    const int mh = wid >> 3;                 // row half
    const int mo = mh << 6;                  // row offset 0 / 64
    const int cg = wid & 7;                  // column group
    const int nc = cg * 32;                  // this wave's 32 output cols
    unsigned short* wrg = (unsigned short*)(smem + 65536) + wid * 2048;  // 4 x 1KB, wave-private

    // ---- P0: transposed NT load (row r = lane + 64*(wid&1)), b128 LDS writes, LN1 partials
    {
        const int r = lane + ((wid & 1) << 6);   // 0..127
        const int eg = wid >> 1;                  // 0..7
        const float* imgb = img + ((size_t)bi * E) * NTOK + n0 + r;
        float ps = 0.f, ps2 = 0.f;
        #pragma unroll
        for (int i = 0; i < 4; ++i) {
            int e0 = eg * 8 + i * 64;
            unsigned pk[4];
            #pragma unroll
            for (int jp = 0; jp < 4; ++jp) {
                float va = __builtin_nontemporal_load(&imgb[(size_t)(e0 + 2 * jp) * NTOK]);
                float vb = __builtin_nontemporal_load(&imgb[(size_t)(e0 + 2 * jp + 1) * NTOK]);
                unsigned short ha = f2bf(va), hb = f2bf(vb);
                float fa = bf2f(ha), fb = bf2f(hb);
                ps += fa + fb; ps2 += fa * fa + fb * fb;
                pk[jp] = (unsigned)ha | ((unsigned)hb << 16);
            }
            int idx = (r * 256 + e0) ^ ((r & 31) << 3);
            uint4 u = {pk[0], pk[1], pk[2], pk[3]};
            *(uint4*)&xsf[idx] = u;
        }
        part_s[r * 9 + eg] = ps;
        part_s2[r * 9 + eg] = ps2;
    }
    __syncthreads();

    // stage2 LN1 (threads 0..127), concurrent with P3a
    if (t < 128) {
        float s = 0.f, s2 = 0.f;
        #pragma unroll
        for (int w = 0; w < 8; ++w) { s += part_s[t * 9 + w]; s2 += part_s2[t * 9 + w]; }
        float m = s * (1.f / 256.f);
        mean_s[t] = m;
        rstd_s[t] = rsqrtf(s2 * (1.f / 256.f) - m * m + 1e-5f);
    }

    // ---- P3a: score partials via MFMA, 16 waves (8 m-tiles x 2 split-K halves)
    {
        const int mt = wid >> 1, kh = wid & 1;
        f32x4 p = {0.f, 0.f, 0.f, 0.f};
        #pragma unroll
        for (int kq = 0; kq < 4; ++kq) {
            int kk = kh * 4 + kq;
            int row = mt * 16 + l15;
            bf16x8 a = *(const bf16x8*)&xsf[(row * 256 + kk * 32 + l4 * 8) ^ ((row & 31) << 3)];
            bf16x8 bfr = *(const bf16x8*)&wks[(bi * 8 + kk) * 512 + lane * 8];
            p = __builtin_amdgcn_mfma_f32_16x16x32_bf16(a, bfr, p, 0, 0, 0);
        }
        #pragma unroll
        for (int rg = 0; rg < 4; ++rg)
            scf[(kh * 128 + mt * 16 + l4 * 4 + rg) * 16 + l15] = p[rg];
    }
    __syncthreads();

    // ---- P3b: LN1-fold + softmax -> alf (one (row,head) per thread)
    {
        int r = t >> 3, h = t & 7;
        float gk0 = Gk[bi * 16 + h], gk1 = Gk[bi * 16 + 8 + h];
        float sb0 = sbk[bi * 16 + h], sb1 = sbk[bi * 16 + 8 + h];
        float ms = mean_s[r], rs = rstd_s[r];
        float raw0 = scf[r * 16 + h] + scf[(128 + r) * 16 + h];
        float raw1 = scf[r * 16 + 8 + h] + scf[(128 + r) * 16 + 8 + h];
        float s0 = rs * (raw0 - ms * gk0) + sb0;
        float s1 = rs * (raw1 - ms * gk1) + sb1;
        float mx = fmaxf(s0, s1);
        float e0 = __expf(s0 - mx), e1 = __expf(s1 - mx);
        float is = __builtin_amdgcn_rcpf(e0 + e1);
        alf[r * 32 + h] = f2bf(e0 * is);
        alf[r * 32 + 8 + h] = f2bf(e1 * is);
        alf[r * 32 + 16 + h] = 0;
        alf[r * 32 + 24 + h] = 0;
    }
    __syncthreads();

    // ---- P3c: attended MFMA + residual; x1 -> xsf (bf16), acc2 seeded with x1 + b2
    f32x4 acc2[4][2];
    {
        f32x4 pa[4][2];
        #pragma unroll
        for (int m = 0; m < 4; ++m)
            #pragma unroll
            for (int n = 0; n < 2; ++n)
                pa[m][n] = f32x4{0.f, 0.f, 0.f, 0.f};
        bf16x8 bv[2];
        #pragma unroll
        for (int n = 0; n < 2; ++n)
            bv[n] = *(const bf16x8*)&wvs[(bi * 16 + cg * 2 + n) * 512 + lane * 8];
        #pragma unroll
        for (int m = 0; m < 4; ++m) {
            int R = mo + m * 16 + l15;
            bf16x8 af = *(const bf16x8*)&alf[R * 32 + l4 * 8];
            #pragma unroll
            for (int n = 0; n < 2; ++n)
                pa[m][n] = __builtin_amdgcn_mfma_f32_16x16x32_bf16(af, bv[n], pa[m][n], 0, 0, 0);
        }
        float bov[2], b2v[2];
        #pragma unroll
        for (int n = 0; n < 2; ++n) {
            bov[n] = pbo[nc + n * 16 + l15];
            b2v[n] = pb2[nc + n * 16 + l15];
        }
        #pragma unroll
        for (int m = 0; m < 4; ++m)
            #pragma unroll
            for (int n = 0; n < 2; ++n)
                #pragma unroll
                for (int rg = 0; rg < 4; ++rg) {
                    int R = mo + m * 16 + l4 * 4 + rg;
                    int C = nc + n * 16 + l15;
                    int xi = (R * 256 + C) ^ ((R & 31) << 3);
                    float x1 = bf2f(xsf[xi]) + pa[m][n][rg] + bov[n];
                    xsf[xi] = f2bf(x1);
                    acc2[m][n][rg] = x1 + b2v[n];
                }
    }

    // preload per-chunk bias; retired by the sync below
    float b1pre[8];
    #pragma unroll
    for (int c = 0; c < 8; ++c)
        b1pre[c] = B1[c * 128 + cg * 16 + l15];
    __syncthreads();   // drains vmcnt -> gll counting starts from 0

    // ---- P4: LN2 stats (wave owns 8 rows)
    for (int rr = 0; rr < 8; ++rr) {
        int r = wid * 8 + rr;
        int idx = (r * 256 + lane * 4) ^ ((r & 31) << 3);
        ushort4 xv = *(const ushort4*)&xsf[idx];
        float v0 = bf2f(xv.x), v1 = bf2f(xv.y), v2 = bf2f(xv.z), v3 = bf2f(xv.w);
        float s = v0 + v1 + v2 + v3;
        float s2 = v0 * v0 + v1 * v1 + v2 * v2 + v3 * v3;
        for (int off = 32; off; off >>= 1) { s += __shfl_down(s, off); s2 += __shfl_down(s2, off); }
        if (lane == 0) {
            float m = s * (1.f / 256.f);
            mean_s[r] = m;
            rstd_s[r] = rsqrtf(s2 * (1.f / 256.f) - m * m + 1e-5f);
        }
    }
    bar_lds();

    // ---- FFN: FC=128, 8 chunks x 16 frags; wave-private 4-slot gll ring, depth-3
    #define ISSUE(S) do { if ((S) <= 127) { \
        const int c_ = (S) >> 4, j_ = (S) & 15; \
        const unsigned short* src_; \
        if (j_ < 8) src_ = w1s + (size_t)((c_ * 64 + j_) * 512) + cg * 4096 + lane * 8; \
        else { const int kkl_ = (j_ - 8) >> 1, og_ = (j_ - 8) & 1; \
               src_ = w2s + (size_t)((((c_ >> 1) * 128 + og_ * 8 + (c_ & 1) * 4 + kkl_)) * 512) + cg * 8192 + lane * 8; } \
        gll16(src_, wrg + ((S) & 3) * 512); \
    } } while (0)

    // prologue: frags 0-2 in flight while we normalize xsf below
    ISSUE(0); ISSUE(1); ISSUE(2);

    // ---- Normalize pass: xsf <- bf16( (x1 - mean)*rstd )  (stats die here)
    {
        int r = t >> 3;
        int c0 = (t & 7) * 32;
        float mr = mean_s[r], rr2 = rstd_s[r];
        #pragma unroll
        for (int j = 0; j < 4; ++j) {
            int idx = (r * 256 + c0 + j * 8) ^ ((r & 31) << 3);
            uint4 u = *(const uint4*)&xsf[idx];
            unsigned pk[4] = {u.x, u.y, u.z, u.w};
            #pragma unroll
            for (int w = 0; w < 4; ++w) {
                float lo = bf2f((unsigned short)(pk[w] & 0xffffu));
                float hi = bf2f((unsigned short)(pk[w] >> 16));
                lo = (lo - mr) * rr2;
                hi = (hi - mr) * rr2;
                pk[w] = (unsigned)f2bf(lo) | ((unsigned)f2bf(hi) << 16);
            }
            uint4 o = {pk[0], pk[1], pk[2], pk[3]};
            *(uint4*)&xsf[idx] = o;
        }
    }
    bar_lds();

    #define G1STEP(S) { \
        const int kb_ = ((S) & 15) * 32 + l4 * 8; \
        bf16x8 x0_ = *(const bf16x8*)&xsf[(((mo +  0 + l15)) * 256 + kb_) ^ (((mo +  0 + l15) & 31) << 3)]; \
        bf16x8 x1_ = *(const bf16x8*)&xsf[(((mo + 16 + l15)) * 256 + kb_) ^ (((mo + 16 + l15) & 31) << 3)]; \
        bf16x8 x2_ = *(const bf16x8*)&xsf[(((mo + 32 + l15)) * 256 + kb_) ^ (((mo + 32 + l15) & 31) << 3)]; \
        bf16x8 x3_ = *(const bf16x8*)&xsf[(((mo + 48 + l15)) * 256 + kb_) ^ (((mo + 48 + l15) & 31) << 3)]; \
        WAITV(S); \
        bf16x8 bf_ = *(const bf16x8*)&wrg[((S) & 3) * 512 + lane * 8]; \
        p[0] = __builtin_amdgcn_mfma_f32_16x16x32_bf16(x0_, bf_, p[0], 0, 0, 0); \
        p[1] = __builtin_amdgcn_mfma_f32_16x16x32_bf16(x1_, bf_, p[1], 0, 0, 0); \
        p[2] = __builtin_amdgcn_mfma_f32_16x16x32_bf16(x2_, bf_, p[2], 0, 0, 0); \
        p[3] = __builtin_amdgcn_mfma_f32_16x16x32_bf16(x3_, bf_, p[3], 0, 0, 0); \
        ISSUE((S) + 3); \
    }

    #define G2STEP(S) { \
        if ((((S) & 15) & 1) == 0) { \
            const int cb_ = (((((S) & 15) - 8) >> 1)) * 32 + l4 * 8; \
            af2[0] = *(const bf16x8*)&hsf[((mo +  0 + l15) * 128 + cb_) ^ ((l15) << 3)]; \
            af2[1] = *(const bf16x8*)&hsf[((mo + 16 + l15) * 128 + cb_) ^ ((l15) << 3)]; \
            af2[2] = *(const bf16x8*)&hsf[((mo + 32 + l15) * 128 + cb_) ^ ((l15) << 3)]; \
            af2[3] = *(const bf16x8*)&hsf[((mo + 48 + l15) * 128 + cb_) ^ ((l15) << 3)]; \
        } \
        WAITV(S); \
        bf16x8 bf_ = *(const bf16x8*)&wrg[((S) & 3) * 512 + lane * 8]; \
        { const int og_ = ((S) & 15) & 1; \
          acc2[0][og_] = __builtin_amdgcn_mfma_f32_16x16x32_bf16(af2[0], bf_, acc2[0][og_], 0, 0, 0); \
          acc2[1][og_] = __builtin_amdgcn_mfma_f32_16x16x32_bf16(af2[1], bf_, acc2[1][og_], 0, 0, 0); \
          acc2[2][og_] = __builtin_amdgcn_mfma_f32_16x16x32_bf16(af2[2], bf_, acc2[2][og_], 0, 0, 0); \
          acc2[3][og_] = __builtin_amdgcn_mfma_f32_16x16x32_bf16(af2[3], bf_, acc2[3][og_], 0, 0, 0); } \
        ISSUE((S) + 3); \
    }

    #define GELUC(C) { \
        const float b1v_ = b1pre[(C)]; \
        _Pragma("unroll") \
        for (int m_ = 0; m_ < 4; ++m_) { \
            _Pragma("unroll") \
            for (int rg_ = 0; rg_ < 4; ++rg_) { \
                int R_ = mo + m_ * 16 + l4 * 4 + rg_; \
                float hp_ = p[m_][rg_] + b1v_; \
                hsf[(R_ * 128 + cg * 16 + l15) ^ ((R_ & 15) << 3)] = f2bf(gelu_fast(hp_)); \
            } \
            p[m_] = f32x4{0.f, 0.f, 0.f, 0.f}; \
        } \
    }

    #define CHUNK(C) { \
        G1STEP((C)*16 + 0); G1STEP((C)*16 + 1); G1STEP((C)*16 + 2); G1STEP((C)*16 + 3); \
        G1STEP((C)*16 + 4); G1STEP((C)*16 + 5); G1STEP((C)*16 + 6); G1STEP((C)*16 + 7); \
        GELUC(C); \
        bar_lds(); \
        G2STEP((C)*16 + 8);  G2STEP((C)*16 + 9);  G2STEP((C)*16 + 10); G2STEP((C)*16 + 11); \
        G2STEP((C)*16 + 12); G2STEP((C)*16 + 13); G2STEP((C)*16 + 14); G2STEP((C)*16 + 15); \
        bar_lds(); \
    }

    f32x4 p[4];
    #pragma unroll
    for (int m = 0; m < 4; ++m) p[m] = f32x4{0.f, 0.f, 0.f, 0.f};
    bf16x8 af2[4];

    CHUNK(0) CHUNK(1) CHUNK(2) CHUNK(3) CHUNK(4) CHUNK(5) CHUNK(6) CHUNK(7)

    #undef ISSUE
    #undef G1STEP
    #undef G2STEP
    #undef GELUC
    #undef CHUNK

    // ---- Epilogue: stage halves in LDS (ring region dead), vectorized NT stores
    #pragma unroll
    for (int h = 0; h < 2; ++h) {
        if ((cg >> 2) == h) {
            #pragma unroll
            for (int m = 0; m < 4; ++m)
                #pragma unroll
                for (int n = 0; n < 2; ++n)
                    #pragma unroll
                    for (int rg = 0; rg < 4; ++rg) {
                        int R = mo + m * 16 + l4 * 4 + rg;
                        int Cl = nc + n * 16 + l15 - h * 128;
                        outsf[(R * 128 + Cl) ^ ((R & 7) << 2)] = acc2[m][n][rg];
                    }
        }
        __syncthreads();
        #pragma unroll
        for (int j = 0; j < 4; ++j) {
            int gidx = j * 1024 + t;
            int e = gidx >> 5;          // 0..127 feature within half
            int part = gidx & 31;       // 32 x f32x4 across 128 rows
            f32x4 v;
            #pragma unroll
            for (int k2 = 0; k2 < 4; ++k2) {
                int nrow = part * 4 + k2;
                v[k2] = outsf[(nrow * 128 + e) ^ ((nrow & 7) << 2)];
            }
            __builtin_nontemporal_store(v,
                (f32x4*)(out + ((size_t)bi * E + h * 128 + e) * NTOK + n0 + part * 4));
        }
        if (h == 0) __syncthreads();
    }
}

extern "C" void kernel_launch(void* const* d_in, const int* in_sizes, int n_in,
                              void* d_out, int out_size, void* d_ws, size_t ws_size,
                              hipStream_t stream) {
    (void)in_sizes; (void)n_in; (void)out_size; (void)ws_size;
    const float* img   = (const float*)d_in[0];
    const float* tt    = (const float*)d_in[1];
    const float* bgt   = (const float*)d_in[2];
    const float* Wp    = (const float*)d_in[3];
    const float* bp    = (const float*)d_in[4];
    const float* g_img = (const float*)d_in[5];
    const float* b_img = (const float*)d_in[6];
    const float* g_tok = (const float*)d_in[7];
    const float* b_tok = (const float*)d_in[8];
    const float* g_ffn = (const float*)d_in[9];
    const float* b_ffn = (const float*)d_in[10];
    const float* Wq    = (const float*)d_in[11];
    const float* Wk    = (const float*)d_in[12];
    const float* Wv    = (const float*)d_in[13];
    const float* bq    = (const float*)d_in[14];
    const float* bk    = (const float*)d_in[15];
    const float* bv    = (const float*)d_in[16];
    const float* Wo    = (const float*)d_in[17];
    const float* bo    = (const float*)d_in[18];
    const float* W1    = (const float*)d_in[19];
    const float* b1    = (const float*)d_in[20];
    const float* W2    = (const float*)d_in[21];
    const float* b2    = (const float*)d_in[22];

    char* ws = (char*)d_ws;
    unsigned short* w1s = (unsigned short*)(ws);              // [0, 524288)
    unsigned short* w2s = (unsigned short*)(ws + 524288);     // [524288, 1048576)
    unsigned short* wks = (unsigned short*)(ws + 1048576);    // [1048576, 1179648)
    unsigned short* wvs = (unsigned short*)(ws + 1179648);    // [1179648, 1441792)
    float*          Gk  = (float*)(ws + 1441792);             // 1 KB
    float*          sbk = (float*)(ws + 1442816);             // 1 KB
    float*          G1  = (float*)(ws + 1443840);             // 4 KB (computed, unused by main)
    float*          B1  = (float*)(ws + 1447936);             // 4 KB

    hipLaunchKernelGGL(prep_kernel, dim3(272), dim3(256), 0, stream,
                       W1, W2, b1, tt, bgt, Wp, bp, g_tok, b_tok, g_img, b_img,
                       Wq, bq, Wk, bk, Wv, bv, Wo, g_ffn, b_ffn,
                       w1s, w2s, wks, wvs, Gk, sbk, G1, B1);
    hipLaunchKernelGGL(fused_main_kernel, dim3(512), dim3(1024), 0, stream,
                       img, bo, b2, w1s, w2s, wks, wvs, Gk, sbk, B1, (float*)d_out);
}

// Round 14
// 232.824 us; speedup vs baseline: 1.1262x; 1.1262x over previous
//
#include <hip/hip_runtime.h>
#include <math.h>

#define E 256
#define TD 128
#define FF 1024
#define NTOK 4096

typedef __attribute__((ext_vector_type(8))) __bf16 bf16x8;
typedef __attribute__((ext_vector_type(4))) float f32x4;

__device__ __forceinline__ unsigned short f2bf(float x) {
    __bf16 b = (__bf16)x;
    return __builtin_bit_cast(unsigned short, b);
}
__device__ __forceinline__ float bf2f(unsigned short h) {
    return __uint_as_float(((unsigned)h) << 16);
}
__device__ __forceinline__ float gelu_fast(float x) {
    float ex = __expf(-x * (1.5957691216057308f + 0.07135481627f * x * x));
    return x * __builtin_amdgcn_rcpf(1.f + ex);
}
// LDS-only barrier: waits ds ops, does NOT drain vmcnt (gll prefetches stay in flight)
__device__ __forceinline__ void bar_lds() {
    __builtin_amdgcn_sched_barrier(0);
    asm volatile("s_waitcnt lgkmcnt(0)" ::: "memory");
    __builtin_amdgcn_s_barrier();
    __builtin_amdgcn_sched_barrier(0);
}
// async global->LDS, 16B/lane: dest = uniform base + lane*16, src = per-lane
__device__ __forceinline__ void gll16(const unsigned short* g, unsigned short* l) {
    __builtin_amdgcn_global_load_lds(
        (const __attribute__((address_space(1))) unsigned int*)g,
        (__attribute__((address_space(3))) unsigned int*)l, 16, 0, 0);
}

#define WVM2 asm volatile("s_waitcnt vmcnt(2)" ::: "memory")
#define WVM1 asm volatile("s_waitcnt vmcnt(1)" ::: "memory")
#define WVM0 asm volatile("s_waitcnt vmcnt(0)" ::: "memory")
// depth-3 issuance with a 4-slot ring (round-12-proven): outstanding = {S,S+1,S+2};
// vmcnt(2) retires S. ISSUE(S+3) targets slot consumed at step S-1 (one-step margin).
#define WAITV(S) do { if ((S) <= 125) { WVM2; } else if ((S) == 126) { WVM1; } else { WVM0; } } while (0)

// ==================== PREP ====================
// blocks 0..255: W1/W2 -> fragment-major bf16 (+G1/B1 on gid<1024) — unchanged.
// blocks 256..287: ONE BLOCK PER (batch, token): bi=(b-256)>>1, j=(b-256)&1.
// Token pipeline halved per block; all writes disjoint in c between the two j-blocks.
__global__ __launch_bounds__(256) void prep_kernel(
    const float* __restrict__ W1, const float* __restrict__ W2, const float* __restrict__ b1,
    const float* __restrict__ tt, const float* __restrict__ bgt,
    const float* __restrict__ Wp, const float* __restrict__ bp,
    const float* __restrict__ g_tok, const float* __restrict__ b_tok,
    const float* __restrict__ g_img, const float* __restrict__ b_img,
    const float* __restrict__ Wq, const float* __restrict__ bq,
    const float* __restrict__ Wk, const float* __restrict__ bk,
    const float* __restrict__ Wv, const float* __restrict__ bv,
    const float* __restrict__ Wo,
    const float* __restrict__ g_ffn, const float* __restrict__ b_ffn,
    unsigned short* __restrict__ w1s, unsigned short* __restrict__ w2s,
    unsigned short* __restrict__ wks, unsigned short* __restrict__ wvs,
    float* __restrict__ Gk, float* __restrict__ sbk,
    float* __restrict__ G1, float* __restrict__ B1)
{
    const int t = threadIdx.x;
    const int lane = t & 63;
    if (blockIdx.x < 256) {
        int gid = blockIdx.x * 256 + t;
        if (gid < 32768) {
            int row = gid >> 5;
            int k0 = (gid & 31) * 8;
            f32x4 wa = *(const f32x4*)(W1 + row * 256 + k0);
            f32x4 wb = *(const f32x4*)(W1 + row * 256 + k0 + 4);
            f32x4 ga = *(const f32x4*)(g_ffn + k0);
            f32x4 gb = *(const f32x4*)(g_ffn + k0 + 4);
            ushort4 o0, o1;
            o0.x = f2bf(wa[0]*ga[0]); o0.y = f2bf(wa[1]*ga[1]);
            o0.z = f2bf(wa[2]*ga[2]); o0.w = f2bf(wa[3]*ga[3]);
            o1.x = f2bf(wb[0]*gb[0]); o1.y = f2bf(wb[1]*gb[1]);
            o1.z = f2bf(wb[2]*gb[2]); o1.w = f2bf(wb[3]*gb[3]);
            int dst = ((row >> 4) * 8 + (k0 >> 5)) * 512 + (((k0 >> 3) & 3) * 16 + (row & 15)) * 8;
            *(ushort4*)(w1s + dst) = o0;
            *(ushort4*)(w1s + dst + 4) = o1;
        } else {
            int g2 = gid - 32768;
            int o = g2 >> 7;
            int f0 = (g2 & 127) * 8;
            f32x4 wa = *(const f32x4*)(W2 + o * 1024 + f0);
            f32x4 wb = *(const f32x4*)(W2 + o * 1024 + f0 + 4);
            ushort4 o0, o1;
            o0.x = f2bf(wa[0]); o0.y = f2bf(wa[1]); o0.z = f2bf(wa[2]); o0.w = f2bf(wa[3]);
            o1.x = f2bf(wb[0]); o1.y = f2bf(wb[1]); o1.z = f2bf(wb[2]); o1.w = f2bf(wb[3]);
            int dst = (((f0 >> 8) * 16 + (o >> 4)) * 8 + ((f0 >> 5) & 7)) * 512
                    + (((f0 >> 3) & 3) * 16 + (o & 15)) * 8;
            *(ushort4*)(w2s + dst) = o0;
            *(ushort4*)(w2s + dst + 4) = o1;
        }
        if (gid < 1024) {
            int row = gid;
            float gacc = 0.f, bacc = 0.f;
            for (int k = 0; k < 256; k += 4) {
                f32x4 w = *(const f32x4*)(W1 + row * 256 + k);
                f32x4 g = *(const f32x4*)(g_ffn + k);
                f32x4 bb = *(const f32x4*)(b_ffn + k);
                gacc += w[0]*g[0] + w[1]*g[1] + w[2]*g[2] + w[3]*g[3];
                bacc += w[0]*bb[0] + w[1]*bb[1] + w[2]*bb[2] + w[3]*bb[3];
            }
            G1[row] = gacc;
            B1[row] = bacc + b1[row];
        }
        return;
    }
    // -------- token block: one (batch, token) --------
    const int bidx = blockIdx.x - 256;
    const int bi = bidx >> 1;
    const int j  = bidx & 1;
    __shared__ float tokL[TD];
    __shared__ float kvn[E];
    __shared__ float ks[E];
    __shared__ float vs[E];
    __shared__ float red[8];
    __shared__ float redk[8][4], redb[8][4];

    if (t < TD) tokL[t] = (j ? bgt : tt)[bi * TD + t];
    __syncthreads();

    // token projection
    {
        float a0 = bp[t];
        const float* wr = Wp + (size_t)t * TD;
        for (int i = 0; i < TD; i += 4) {
            f32x4 w = *(const f32x4*)(wr + i);
            f32x4 x0 = *(const f32x4*)(&tokL[i]);
            a0 += w[0]*x0[0] + w[1]*x0[1] + w[2]*x0[2] + w[3]*x0[3];
        }
        kvn[t] = a0;
    }
    __syncthreads();
    // layernorm(g_tok, b_tok)
    {
        float v = kvn[t];
        float s = v, s2 = v * v;
        for (int off = 32; off; off >>= 1) { s += __shfl_down(s, off); s2 += __shfl_down(s2, off); }
        if (lane == 0) { red[t >> 6] = s; red[4 + (t >> 6)] = s2; }
        __syncthreads();
        float S = red[0] + red[1] + red[2] + red[3];
        float S2 = red[4] + red[5] + red[6] + red[7];
        float m = S * (1.f / E);
        float rs = rsqrtf(S2 * (1.f / E) - m * m + 1e-5f);
        kvn[t] = (v - m) * rs * g_tok[t] + b_tok[t];
    }
    __syncthreads();
    // k, v projections
    {
        float k0 = bk[t], v0 = bv[t];
        const float* wkr = Wk + (size_t)t * E;
        const float* wvr = Wv + (size_t)t * E;
        for (int i = 0; i < E; i += 4) {
            f32x4 wk4 = *(const f32x4*)(wkr + i);
            f32x4 wv4 = *(const f32x4*)(wvr + i);
            f32x4 x0 = *(const f32x4*)(&kvn[i]);
            k0 += wk4[0]*x0[0] + wk4[1]*x0[1] + wk4[2]*x0[2] + wk4[3]*x0[3];
            v0 += wv4[0]*x0[0] + wv4[1]*x0[1] + wv4[2]*x0[2] + wv4[3]*x0[3];
        }
        ks[t] = k0; vs[t] = v0;
    }
    __syncthreads();
    const float inv = 0.17677669529663687f;
    const float gi = g_img[t], bimg = b_img[t];
    for (int ci = 0; ci < 8; ++ci) {
        const int c = j * 8 + ci, h = ci;
        float awk = 0.f, awv = 0.f;
        const float* wqc = Wq + (size_t)(h * 32) * E + t;
        const float* wor = Wo + (size_t)t * E + h * 32;
        #pragma unroll
        for (int d = 0; d < 32; d += 4) {
            f32x4 kv = *(const f32x4*)(&ks[h * 32 + d]);
            f32x4 vv = *(const f32x4*)(&vs[h * 32 + d]);
            f32x4 wo4 = *(const f32x4*)(wor + d);
            awk += kv[0]*wqc[(size_t)(d+0)*E] + kv[1]*wqc[(size_t)(d+1)*E]
                 + kv[2]*wqc[(size_t)(d+2)*E] + kv[3]*wqc[(size_t)(d+3)*E];
            awv += wo4[0]*vv[0] + wo4[1]*vv[1] + wo4[2]*vv[2] + wo4[3]*vv[3];
        }
        float base = awk * inv;
        wks[(bi * 8 + (t >> 5)) * 512 + (((t >> 3) & 3) * 16 + c) * 8 + (t & 7)] = f2bf(gi * base);
        wvs[(bi * 16 + (t >> 4)) * 512 + ((c >> 3) * 16 + (t & 15)) * 8 + (c & 7)] = f2bf(awv);
        float rk = gi * base, rb = bimg * base;
        for (int off = 32; off; off >>= 1) { rk += __shfl_down(rk, off); rb += __shfl_down(rb, off); }
        if (lane == 0) { redk[ci][t >> 6] = rk; redb[ci][t >> 6] = rb; }
    }
    // zero-pad K=32 region: this block covers c2 = 16 + j*8 + ci (disjoint between j-blocks)
    #pragma unroll
    for (int ci = 0; ci < 8; ++ci) {
        int c2 = 16 + j * 8 + ci;
        wvs[(bi * 16 + (t >> 4)) * 512 + ((c2 >> 3) * 16 + (t & 15)) * 8 + (c2 & 7)] = 0;
    }
    __syncthreads();
    if (t < 8) {
        int ci = t, c = j * 8 + ci, h = ci;
        float s = 0.f;
        for (int d = 0; d < 32; ++d) s += bq[h * 32 + d] * ks[h * 32 + d];
        Gk[bi * 16 + c] = redk[ci][0] + redk[ci][1] + redk[ci][2] + redk[ci][3];
        sbk[bi * 16 + c] = redb[ci][0] + redb[ci][1] + redb[ci][2] + redb[ci][3] + s * inv;
    }
}

// ==================== FUSED MAIN ==================== (byte-identical to round 12)
// 64 rows/block, 512 thr (8 waves), 2 blk/CU (LDS = 81920 exactly).
// xsf pre-normalized to LN2(x1)-hat before FFN -> stats die, 4-slot depth-3 gll ring.
__global__ __launch_bounds__(512, 4) void fused_main_kernel(
    const float* __restrict__ img,
    const float* __restrict__ pbo, const float* __restrict__ pb2,
    const unsigned short* __restrict__ w1s, const unsigned short* __restrict__ w2s,
    const unsigned short* __restrict__ wks, const unsigned short* __restrict__ wvs,
    const float* __restrict__ Gk, const float* __restrict__ sbk,
    const float* __restrict__ B1,
    float* __restrict__ out)
{
    __shared__ __align__(16) char smem[81920];
    unsigned short* xsf = (unsigned short*)smem;            // [64*256] bf16, swz (r&31)<<3 (32K)
    // ring @ 32768: 8 waves x 4 slots x 1KB = 32K
    unsigned short* hsf = (unsigned short*)(smem + 65536);  // [64*128] bf16, swz (r&15)<<3 (16K)
    float* part_s  = (float*)(smem + 32768);                // [64*9]
    float* part_s2 = (float*)(smem + 35072);                // [64*9]
    unsigned short* alf = (unsigned short*)(smem + 32768);  // [64*32] (after parts dead)
    float* scf     = (float*)(smem + 37376);                // [2*64*16]
    float* outsf   = (float*)(smem + 32768);                // [64*128] f32 epilogue (ring dead)
    float* mean_s  = (float*)(smem + 65536);                // [64]
    float* rstd_s  = (float*)(smem + 65792);                // [64]

    const int t = threadIdx.x;
    const int lane = t & 63;
    const int wid = t >> 6;
    const int l15 = lane & 15;
    const int l4 = lane >> 4;
    const int bi = blockIdx.x >> 6;
    const int n0 = (blockIdx.x & 63) << 6;
    const int nc = wid * 32;
    unsigned short* wrg = (unsigned short*)(smem + 32768) + wid * 2048;  // 4 slots x 1KB, wave-private

    // ---- P0: transposed NT load, packed b128 LDS writes, fused LN1 partials
    {
        const float* imgb = img + ((size_t)bi * E) * NTOK + n0 + lane;
        float ps = 0.f, ps2 = 0.f;
        #pragma unroll
        for (int i = 0; i < 4; ++i) {
            int e0 = wid * 8 + i * 64;
            unsigned pk[4];
            #pragma unroll
            for (int jp = 0; jp < 4; ++jp) {
                float va = __builtin_nontemporal_load(&imgb[(size_t)(e0 + 2 * jp) * NTOK]);
                float vb = __builtin_nontemporal_load(&imgb[(size_t)(e0 + 2 * jp + 1) * NTOK]);
                unsigned short ha = f2bf(va), hb = f2bf(vb);
                float fa = bf2f(ha), fb = bf2f(hb);
                ps += fa + fb; ps2 += fa * fa + fb * fb;
                pk[jp] = (unsigned)ha | ((unsigned)hb << 16);
            }
            int idx = (lane * 256 + e0) ^ ((lane & 31) << 3);
            uint4 u = {pk[0], pk[1], pk[2], pk[3]};
            *(uint4*)&xsf[idx] = u;
        }
        part_s[lane * 9 + wid] = ps;
        part_s2[lane * 9 + wid] = ps2;
    }
    __syncthreads();

    if (t < 64) {
        float s = 0.f, s2 = 0.f;
        #pragma unroll
        for (int w = 0; w < 8; ++w) { s += part_s[t * 9 + w]; s2 += part_s2[t * 9 + w]; }
        float m = s * (1.f / 256.f);
        mean_s[t] = m;
        rstd_s[t] = rsqrtf(s2 * (1.f / 256.f) - m * m + 1e-5f);
    }

    // ---- P3a: score partials via MFMA, all 8 waves (split-K)
    {
        const int mt = wid >> 1, kh = wid & 1;
        f32x4 p = {0.f, 0.f, 0.f, 0.f};
        #pragma unroll
        for (int kq = 0; kq < 4; ++kq) {
            int kk = kh * 4 + kq;
            int row = mt * 16 + l15;
            bf16x8 a = *(const bf16x8*)&xsf[(row * 256 + kk * 32 + l4 * 8) ^ ((row & 31) << 3)];
            bf16x8 bfr = *(const bf16x8*)&wks[(bi * 8 + kk) * 512 + lane * 8];
            p = __builtin_amdgcn_mfma_f32_16x16x32_bf16(a, bfr, p, 0, 0, 0);
        }
        #pragma unroll
        for (int rg = 0; rg < 4; ++rg)
            scf[(kh * 64 + mt * 16 + l4 * 4 + rg) * 16 + l15] = p[rg];
    }
    __syncthreads();

    // ---- P3b: LN1-fold + softmax -> alf
    {
        int r = t >> 3, h = t & 7;
        float gk0 = Gk[bi * 16 + h], gk1 = Gk[bi * 16 + 8 + h];
        float sb0 = sbk[bi * 16 + h], sb1 = sbk[bi * 16 + 8 + h];
        float ms = mean_s[r], rs = rstd_s[r];
        float raw0 = scf[r * 16 + h] + scf[(64 + r) * 16 + h];
        float raw1 = scf[r * 16 + 8 + h] + scf[(64 + r) * 16 + 8 + h];
        float s0 = rs * (raw0 - ms * gk0) + sb0;
        float s1 = rs * (raw1 - ms * gk1) + sb1;
        float mx = fmaxf(s0, s1);
        float e0 = __expf(s0 - mx), e1 = __expf(s1 - mx);
        float is = __builtin_amdgcn_rcpf(e0 + e1);
        alf[r * 32 + h] = f2bf(e0 * is);
        alf[r * 32 + 8 + h] = f2bf(e1 * is);
        alf[r * 32 + 16 + h] = 0;
        alf[r * 32 + 24 + h] = 0;
    }
    __syncthreads();

    // ---- P3c: attended MFMA + residual; x1 -> xsf (bf16), acc2 seeded with x1 + b2
    f32x4 acc2[4][2];
    {
        f32x4 pa[4][2];
        #pragma unroll
        for (int m = 0; m < 4; ++m)
            #pragma unroll
            for (int n = 0; n < 2; ++n)
                pa[m][n] = f32x4{0.f, 0.f, 0.f, 0.f};
        bf16x8 bv[2];
        #pragma unroll
        for (int n = 0; n < 2; ++n)
            bv[n] = *(const bf16x8*)&wvs[(bi * 16 + wid * 2 + n) * 512 + lane * 8];
        #pragma unroll
        for (int m = 0; m < 4; ++m) {
            bf16x8 af = *(const bf16x8*)&alf[(m * 16 + l15) * 32 + l4 * 8];
            #pragma unroll
            for (int n = 0; n < 2; ++n)
                pa[m][n] = __builtin_amdgcn_mfma_f32_16x16x32_bf16(af, bv[n], pa[m][n], 0, 0, 0);
        }
        float bov[2], b2v[2];
        #pragma unroll
        for (int n = 0; n < 2; ++n) {
            bov[n] = pbo[nc + n * 16 + l15];
            b2v[n] = pb2[nc + n * 16 + l15];
        }
        #pragma unroll
        for (int m = 0; m < 4; ++m)
            #pragma unroll
            for (int n = 0; n < 2; ++n)
                #pragma unroll
                for (int rg = 0; rg < 4; ++rg) {
                    int R = m * 16 + l4 * 4 + rg;
                    int C = nc + n * 16 + l15;
                    int xi = (R * 256 + C) ^ ((R & 31) << 3);
                    float x1 = bf2f(xsf[xi]) + pa[m][n][rg] + bov[n];
                    xsf[xi] = f2bf(x1);
                    acc2[m][n][rg] = x1 + b2v[n];
                }
    }

    // preload per-chunk bias (B1 includes b_ffn@W1^T + b1); retired by the sync below
    float b1pre[8];
    #pragma unroll
    for (int c = 0; c < 8; ++c)
        b1pre[c] = B1[c * 128 + wid * 16 + l15];
    __syncthreads();   // also drains vmcnt -> gll counting below starts from 0

    // ---- P4: LN2 stats
    for (int rr = 0; rr < 8; ++rr) {
        int r = wid * 8 + rr;
        int idx = (r * 256 + lane * 4) ^ ((r & 31) << 3);
        ushort4 xv = *(const ushort4*)&xsf[idx];
        float v0 = bf2f(xv.x), v1 = bf2f(xv.y), v2 = bf2f(xv.z), v3 = bf2f(xv.w);
        float s = v0 + v1 + v2 + v3;
        float s2 = v0 * v0 + v1 * v1 + v2 * v2 + v3 * v3;
        for (int off = 32; off; off >>= 1) { s += __shfl_down(s, off); s2 += __shfl_down(s2, off); }
        if (lane == 0) {
            float m = s * (1.f / 256.f);
            mean_s[r] = m;
            rstd_s[r] = rsqrtf(s2 * (1.f / 256.f) - m * m + 1e-5f);
        }
    }
    bar_lds();

    // ---- FFN: FC=128, 8 chunks x 16 frags; wave-private 4-slot gll ring, depth-3
    #define ISSUE(S) do { if ((S) <= 127) { \
        const int c_ = (S) >> 4, j_ = (S) & 15; \
        const unsigned short* src_; \
        if (j_ < 8) src_ = w1s + (size_t)((c_ * 64 + j_) * 512) + wid * 4096 + lane * 8; \
        else { const int kkl_ = (j_ - 8) >> 1, og_ = (j_ - 8) & 1; \
               src_ = w2s + (size_t)((((c_ >> 1) * 128 + og_ * 8 + (c_ & 1) * 4 + kkl_)) * 512) + wid * 8192 + lane * 8; } \
        gll16(src_, wrg + ((S) & 3) * 512); \
    } } while (0)

    // prologue: frags 0-2 in flight while we normalize xsf below
    ISSUE(0); ISSUE(1); ISSUE(2);

    // ---- Normalize pass: xsf <- bf16( (x1 - mean)*rstd )  (LN2-hat; stats die here)
    {
        int r = t >> 3;
        int c0 = (t & 7) * 32;
        float mr = mean_s[r], rr2 = rstd_s[r];
        #pragma unroll
        for (int j = 0; j < 4; ++j) {
            int idx = (r * 256 + c0 + j * 8) ^ ((r & 31) << 3);
            uint4 u = *(const uint4*)&xsf[idx];
            unsigned pk[4] = {u.x, u.y, u.z, u.w};
            #pragma unroll
            for (int w = 0; w < 4; ++w) {
                float lo = bf2f((unsigned short)(pk[w] & 0xffffu));
                float hi = bf2f((unsigned short)(pk[w] >> 16));
                lo = (lo - mr) * rr2;
                hi = (hi - mr) * rr2;
                pk[w] = (unsigned)f2bf(lo) | ((unsigned)f2bf(hi) << 16);
            }
            uint4 o = {pk[0], pk[1], pk[2], pk[3]};
            *(uint4*)&xsf[idx] = o;
        }
    }
    bar_lds();

    #define G1STEP(S) { \
        const int kb_ = ((S) & 15) * 32 + l4 * 8; \
        bf16x8 x0_ = *(const bf16x8*)&xsf[((l15) * 256 + kb_) ^ (((l15) & 31) << 3)]; \
        bf16x8 x1_ = *(const bf16x8*)&xsf[((16 + l15) * 256 + kb_) ^ (((16 + l15) & 31) << 3)]; \
        bf16x8 x2_ = *(const bf16x8*)&xsf[((32 + l15) * 256 + kb_) ^ (((32 + l15) & 31) << 3)]; \
        bf16x8 x3_ = *(const bf16x8*)&xsf[((48 + l15) * 256 + kb_) ^ (((48 + l15) & 31) << 3)]; \
        WAITV(S); \
        bf16x8 bf_ = *(const bf16x8*)&wrg[((S) & 3) * 512 + lane * 8]; \
        p[0] = __builtin_amdgcn_mfma_f32_16x16x32_bf16(x0_, bf_, p[0], 0, 0, 0); \
        p[1] = __builtin_amdgcn_mfma_f32_16x16x32_bf16(x1_, bf_, p[1], 0, 0, 0); \
        p[2] = __builtin_amdgcn_mfma_f32_16x16x32_bf16(x2_, bf_, p[2], 0, 0, 0); \
        p[3] = __builtin_amdgcn_mfma_f32_16x16x32_bf16(x3_, bf_, p[3], 0, 0, 0); \
        ISSUE((S) + 3); \
    }

    #define G2STEP(S) { \
        if ((((S) & 15) & 1) == 0) { \
            const int cb_ = (((((S) & 15) - 8) >> 1)) * 32 + l4 * 8; \
            af2[0] = *(const bf16x8*)&hsf[((l15) * 128 + cb_) ^ ((l15) << 3)]; \
            af2[1] = *(const bf16x8*)&hsf[((16 + l15) * 128 + cb_) ^ ((l15) << 3)]; \
            af2[2] = *(const bf16x8*)&hsf[((32 + l15) * 128 + cb_) ^ ((l15) << 3)]; \
            af2[3] = *(const bf16x8*)&hsf[((48 + l15) * 128 + cb_) ^ ((l15) << 3)]; \
        } \
        WAITV(S); \
        bf16x8 bf_ = *(const bf16x8*)&wrg[((S) & 3) * 512 + lane * 8]; \
        { const int og_ = ((S) & 15) & 1; \
          acc2[0][og_] = __builtin_amdgcn_mfma_f32_16x16x32_bf16(af2[0], bf_, acc2[0][og_], 0, 0, 0); \
          acc2[1][og_] = __builtin_amdgcn_mfma_f32_16x16x32_bf16(af2[1], bf_, acc2[1][og_], 0, 0, 0); \
          acc2[2][og_] = __builtin_amdgcn_mfma_f32_16x16x32_bf16(af2[2], bf_, acc2[2][og_], 0, 0, 0); \
          acc2[3][og_] = __builtin_amdgcn_mfma_f32_16x16x32_bf16(af2[3], bf_, acc2[3][og_], 0, 0, 0); } \
        ISSUE((S) + 3); \
    }

    #define GELUC(C) { \
        const float b1v_ = b1pre[(C)]; \
        _Pragma("unroll") \
        for (int m_ = 0; m_ < 4; ++m_) { \
            _Pragma("unroll") \
            for (int rg_ = 0; rg_ < 4; ++rg_) { \
                int R_ = m_ * 16 + l4 * 4 + rg_; \
                float hp_ = p[m_][rg_] + b1v_; \
                hsf[(R_ * 128 + wid * 16 + l15) ^ ((R_ & 15) << 3)] = f2bf(gelu_fast(hp_)); \
            } \
            p[m_] = f32x4{0.f, 0.f, 0.f, 0.f}; \
        } \
    }

    #define CHUNK(C) { \
        G1STEP((C)*16 + 0); G1STEP((C)*16 + 1); G1STEP((C)*16 + 2); G1STEP((C)*16 + 3); \
        G1STEP((C)*16 + 4); G1STEP((C)*16 + 5); G1STEP((C)*16 + 6); G1STEP((C)*16 + 7); \
        GELUC(C); \
        bar_lds(); \
        G2STEP((C)*16 + 8);  G2STEP((C)*16 + 9);  G2STEP((C)*16 + 10); G2STEP((C)*16 + 11); \
        G2STEP((C)*16 + 12); G2STEP((C)*16 + 13); G2STEP((C)*16 + 14); G2STEP((C)*16 + 15); \
        bar_lds(); \
    }

    f32x4 p[4];
    #pragma unroll
    for (int m = 0; m < 4; ++m) p[m] = f32x4{0.f, 0.f, 0.f, 0.f};
    bf16x8 af2[4];

    CHUNK(0) CHUNK(1) CHUNK(2) CHUNK(3) CHUNK(4) CHUNK(5) CHUNK(6) CHUNK(7)

    #undef ISSUE
    #undef G1STEP
    #undef G2STEP
    #undef GELUC
    #undef CHUNK

    // ---- Epilogue: stage halves in LDS (ring region dead), vectorized NT stores
    #pragma unroll
    for (int h = 0; h < 2; ++h) {
        if ((wid >> 2) == h) {
            #pragma unroll
            for (int m = 0; m < 4; ++m)
                #pragma unroll
                for (int n = 0; n < 2; ++n)
                    #pragma unroll
                    for (int rg = 0; rg < 4; ++rg) {
                        int R = m * 16 + l4 * 4 + rg;
                        int Cl = nc + n * 16 + l15 - h * 128;
                        outsf[(R * 128 + Cl) ^ ((R & 7) << 2)] = acc2[m][n][rg];
                    }
        }
        __syncthreads();
        #pragma unroll
        for (int j = 0; j < 4; ++j) {
            int gidx = j * 512 + t;
            int e = gidx >> 4;
            int part = gidx & 15;
            f32x4 v;
            #pragma unroll
            for (int k2 = 0; k2 < 4; ++k2) {
                int nrow = part * 4 + k2;
                v[k2] = outsf[(nrow * 128 + e) ^ ((nrow & 7) << 2)];
            }
            __builtin_nontemporal_store(v,
                (f32x4*)(out + ((size_t)bi * E + h * 128 + e) * NTOK + n0 + part * 4));
        }
        if (h == 0) __syncthreads();
    }
}

extern "C" void kernel_launch(void* const* d_in, const int* in_sizes, int n_in,
                              void* d_out, int out_size, void* d_ws, size_t ws_size,
                              hipStream_t stream) {
    (void)in_sizes; (void)n_in; (void)out_size; (void)ws_size;
    const float* img   = (const float*)d_in[0];
    const float* tt    = (const float*)d_in[1];
    const float* bgt   = (const float*)d_in[2];
    const float* Wp    = (const float*)d_in[3];
    const float* bp    = (const float*)d_in[4];
    const float* g_img = (const float*)d_in[5];
    const float* b_img = (const float*)d_in[6];
    const float* g_tok = (const float*)d_in[7];
    const float* b_tok = (const float*)d_in[8];
    const float* g_ffn = (const float*)d_in[9];
    const float* b_ffn = (const float*)d_in[10];
    const float* Wq    = (const float*)d_in[11];
    const float* Wk    = (const float*)d_in[12];
    const float* Wv    = (const float*)d_in[13];
    const float* bq    = (const float*)d_in[14];
    const float* bk    = (const float*)d_in[15];
    const float* bv    = (const float*)d_in[16];
    const float* Wo    = (const float*)d_in[17];
    const float* bo    = (const float*)d_in[18];
    const float* W1    = (const float*)d_in[19];
    const float* b1    = (const float*)d_in[20];
    const float* W2    = (const float*)d_in[21];
    const float* b2    = (const float*)d_in[22];

    char* ws = (char*)d_ws;
    unsigned short* w1s = (unsigned short*)(ws);              // [0, 524288)
    unsigned short* w2s = (unsigned short*)(ws + 524288);     // [524288, 1048576)
    unsigned short* wks = (unsigned short*)(ws + 1048576);    // [1048576, 1179648)
    unsigned short* wvs = (unsigned short*)(ws + 1179648);    // [1179648, 1441792)
    float*          Gk  = (float*)(ws + 1441792);             // 1 KB
    float*          sbk = (float*)(ws + 1442816);             // 1 KB
    float*          G1  = (float*)(ws + 1443840);             // 4 KB (computed, unused by main)
    float*          B1  = (float*)(ws + 1447936);             // 4 KB

    hipLaunchKernelGGL(prep_kernel, dim3(288), dim3(256), 0, stream,
                       W1, W2, b1, tt, bgt, Wp, bp, g_tok, b_tok, g_img, b_img,
                       Wq, bq, Wk, bk, Wv, bv, Wo, g_ffn, b_ffn,
                       w1s, w2s, wks, wvs, Gk, sbk, G1, B1);
    hipLaunchKernelGGL(fused_main_kernel, dim3(1024), dim3(512), 0, stream,
                       img, bo, b2, w1s, w2s, wks, wvs, Gk, sbk, B1, (float*)d_out);
}

// Round 15
// 232.383 us; speedup vs baseline: 1.1283x; 1.0019x over previous
//
#include <hip/hip_runtime.h>
#include <math.h>

#define E 256
#define TD 128
#define FF 1024
#define NTOK 4096

typedef __attribute__((ext_vector_type(8))) __bf16 bf16x8;
typedef __attribute__((ext_vector_type(4))) float f32x4;

__device__ __forceinline__ unsigned short f2bf(float x) {
    __bf16 b = (__bf16)x;
    return __builtin_bit_cast(unsigned short, b);
}
__device__ __forceinline__ float bf2f(unsigned short h) {
    return __uint_as_float(((unsigned)h) << 16);
}
__device__ __forceinline__ float gelu_fast(float x) {
    float ex = __expf(-x * (1.5957691216057308f + 0.07135481627f * x * x));
    return x * __builtin_amdgcn_rcpf(1.f + ex);
}
// LDS-only barrier: waits ds ops, does NOT drain vmcnt (gll prefetches stay in flight)
__device__ __forceinline__ void bar_lds() {
    __builtin_amdgcn_sched_barrier(0);
    asm volatile("s_waitcnt lgkmcnt(0)" ::: "memory");
    __builtin_amdgcn_s_barrier();
    __builtin_amdgcn_sched_barrier(0);
}
// async global->LDS, 16B/lane: dest = uniform base + lane*16, src = per-lane
__device__ __forceinline__ void gll16(const unsigned short* g, unsigned short* l) {
    __builtin_amdgcn_global_load_lds(
        (const __attribute__((address_space(1))) unsigned int*)g,
        (__attribute__((address_space(3))) unsigned int*)l, 16, 0, 0);
}

#define WVM2 asm volatile("s_waitcnt vmcnt(2)" ::: "memory")
#define WVM1 asm volatile("s_waitcnt vmcnt(1)" ::: "memory")
#define WVM0 asm volatile("s_waitcnt vmcnt(0)" ::: "memory")
// depth-3 issuance with a 4-slot ring (round-12-proven): outstanding = {S,S+1,S+2};
// vmcnt(2) retires S. ISSUE(S+3) targets slot consumed at step S-1 (one-step margin).
#define WAITV(S) do { if ((S) <= 125) { WVM2; } else if ((S) == 126) { WVM1; } else { WVM0; } } while (0)

// ==================== PREP ==================== (identical to round 14)
__global__ __launch_bounds__(256) void prep_kernel(
    const float* __restrict__ W1, const float* __restrict__ W2, const float* __restrict__ b1,
    const float* __restrict__ tt, const float* __restrict__ bgt,
    const float* __restrict__ Wp, const float* __restrict__ bp,
    const float* __restrict__ g_tok, const float* __restrict__ b_tok,
    const float* __restrict__ g_img, const float* __restrict__ b_img,
    const float* __restrict__ Wq, const float* __restrict__ bq,
    const float* __restrict__ Wk, const float* __restrict__ bk,
    const float* __restrict__ Wv, const float* __restrict__ bv,
    const float* __restrict__ Wo,
    const float* __restrict__ g_ffn, const float* __restrict__ b_ffn,
    unsigned short* __restrict__ w1s, unsigned short* __restrict__ w2s,
    unsigned short* __restrict__ wks, unsigned short* __restrict__ wvs,
    float* __restrict__ Gk, float* __restrict__ sbk,
    float* __restrict__ G1, float* __restrict__ B1)
{
    const int t = threadIdx.x;
    const int lane = t & 63;
    if (blockIdx.x < 256) {
        int gid = blockIdx.x * 256 + t;
        if (gid < 32768) {
            int row = gid >> 5;
            int k0 = (gid & 31) * 8;
            f32x4 wa = *(const f32x4*)(W1 + row * 256 + k0);
            f32x4 wb = *(const f32x4*)(W1 + row * 256 + k0 + 4);
            f32x4 ga = *(const f32x4*)(g_ffn + k0);
            f32x4 gb = *(const f32x4*)(g_ffn + k0 + 4);
            ushort4 o0, o1;
            o0.x = f2bf(wa[0]*ga[0]); o0.y = f2bf(wa[1]*ga[1]);
            o0.z = f2bf(wa[2]*ga[2]); o0.w = f2bf(wa[3]*ga[3]);
            o1.x = f2bf(wb[0]*gb[0]); o1.y = f2bf(wb[1]*gb[1]);
            o1.z = f2bf(wb[2]*gb[2]); o1.w = f2bf(wb[3]*gb[3]);
            int dst = ((row >> 4) * 8 + (k0 >> 5)) * 512 + (((k0 >> 3) & 3) * 16 + (row & 15)) * 8;
            *(ushort4*)(w1s + dst) = o0;
            *(ushort4*)(w1s + dst + 4) = o1;
        } else {
            int g2 = gid - 32768;
            int o = g2 >> 7;
            int f0 = (g2 & 127) * 8;
            f32x4 wa = *(const f32x4*)(W2 + o * 1024 + f0);
            f32x4 wb = *(const f32x4*)(W2 + o * 1024 + f0 + 4);
            ushort4 o0, o1;
            o0.x = f2bf(wa[0]); o0.y = f2bf(wa[1]); o0.z = f2bf(wa[2]); o0.w = f2bf(wa[3]);
            o1.x = f2bf(wb[0]); o1.y = f2bf(wb[1]); o1.z = f2bf(wb[2]); o1.w = f2bf(wb[3]);
            int dst = (((f0 >> 8) * 16 + (o >> 4)) * 8 + ((f0 >> 5) & 7)) * 512
                    + (((f0 >> 3) & 3) * 16 + (o & 15)) * 8;
            *(ushort4*)(w2s + dst) = o0;
            *(ushort4*)(w2s + dst + 4) = o1;
        }
        if (gid < 1024) {
            int row = gid;
            float gacc = 0.f, bacc = 0.f;
            for (int k = 0; k < 256; k += 4) {
                f32x4 w = *(const f32x4*)(W1 + row * 256 + k);
                f32x4 g = *(const f32x4*)(g_ffn + k);
                f32x4 bb = *(const f32x4*)(b_ffn + k);
                gacc += w[0]*g[0] + w[1]*g[1] + w[2]*g[2] + w[3]*g[3];
                bacc += w[0]*bb[0] + w[1]*bb[1] + w[2]*bb[2] + w[3]*bb[3];
            }
            G1[row] = gacc;
            B1[row] = bacc + b1[row];
        }
        return;
    }
    // -------- token block: one (batch, token) --------
    const int bidx = blockIdx.x - 256;
    const int bi = bidx >> 1;
    const int j  = bidx & 1;
    __shared__ float tokL[TD];
    __shared__ float kvn[E];
    __shared__ float ks[E];
    __shared__ float vs[E];
    __shared__ float red[8];
    __shared__ float redk[8][4], redb[8][4];

    if (t < TD) tokL[t] = (j ? bgt : tt)[bi * TD + t];
    __syncthreads();

    {
        float a0 = bp[t];
        const float* wr = Wp + (size_t)t * TD;
        for (int i = 0; i < TD; i += 4) {
            f32x4 w = *(const f32x4*)(wr + i);
            f32x4 x0 = *(const f32x4*)(&tokL[i]);
            a0 += w[0]*x0[0] + w[1]*x0[1] + w[2]*x0[2] + w[3]*x0[3];
        }
        kvn[t] = a0;
    }
    __syncthreads();
    {
        float v = kvn[t];
        float s = v, s2 = v * v;
        for (int off = 32; off; off >>= 1) { s += __shfl_down(s, off); s2 += __shfl_down(s2, off); }
        if (lane == 0) { red[t >> 6] = s; red[4 + (t >> 6)] = s2; }
        __syncthreads();
        float S = red[0] + red[1] + red[2] + red[3];
        float S2 = red[4] + red[5] + red[6] + red[7];
        float m = S * (1.f / E);
        float rs = rsqrtf(S2 * (1.f / E) - m * m + 1e-5f);
        kvn[t] = (v - m) * rs * g_tok[t] + b_tok[t];
    }
    __syncthreads();
    {
        float k0 = bk[t], v0 = bv[t];
        const float* wkr = Wk + (size_t)t * E;
        const float* wvr = Wv + (size_t)t * E;
        for (int i = 0; i < E; i += 4) {
            f32x4 wk4 = *(const f32x4*)(wkr + i);
            f32x4 wv4 = *(const f32x4*)(wvr + i);
            f32x4 x0 = *(const f32x4*)(&kvn[i]);
            k0 += wk4[0]*x0[0] + wk4[1]*x0[1] + wk4[2]*x0[2] + wk4[3]*x0[3];
            v0 += wv4[0]*x0[0] + wv4[1]*x0[1] + wv4[2]*x0[2] + wv4[3]*x0[3];
        }
        ks[t] = k0; vs[t] = v0;
    }
    __syncthreads();
    const float inv = 0.17677669529663687f;
    const float gi = g_img[t], bimg = b_img[t];
    for (int ci = 0; ci < 8; ++ci) {
        const int c = j * 8 + ci, h = ci;
        float awk = 0.f, awv = 0.f;
        const float* wqc = Wq + (size_t)(h * 32) * E + t;
        const float* wor = Wo + (size_t)t * E + h * 32;
        #pragma unroll
        for (int d = 0; d < 32; d += 4) {
            f32x4 kv = *(const f32x4*)(&ks[h * 32 + d]);
            f32x4 vv = *(const f32x4*)(&vs[h * 32 + d]);
            f32x4 wo4 = *(const f32x4*)(wor + d);
            awk += kv[0]*wqc[(size_t)(d+0)*E] + kv[1]*wqc[(size_t)(d+1)*E]
                 + kv[2]*wqc[(size_t)(d+2)*E] + kv[3]*wqc[(size_t)(d+3)*E];
            awv += wo4[0]*vv[0] + wo4[1]*vv[1] + wo4[2]*vv[2] + wo4[3]*vv[3];
        }
        float base = awk * inv;
        wks[(bi * 8 + (t >> 5)) * 512 + (((t >> 3) & 3) * 16 + c) * 8 + (t & 7)] = f2bf(gi * base);
        wvs[(bi * 16 + (t >> 4)) * 512 + ((c >> 3) * 16 + (t & 15)) * 8 + (c & 7)] = f2bf(awv);
        float rk = gi * base, rb = bimg * base;
        for (int off = 32; off; off >>= 1) { rk += __shfl_down(rk, off); rb += __shfl_down(rb, off); }
        if (lane == 0) { redk[ci][t >> 6] = rk; redb[ci][t >> 6] = rb; }
    }
    #pragma unroll
    for (int ci = 0; ci < 8; ++ci) {
        int c2 = 16 + j * 8 + ci;
        wvs[(bi * 16 + (t >> 4)) * 512 + ((c2 >> 3) * 16 + (t & 15)) * 8 + (c2 & 7)] = 0;
    }
    __syncthreads();
    if (t < 8) {
        int ci = t, c = j * 8 + ci, h = ci;
        float s = 0.f;
        for (int d = 0; d < 32; ++d) s += bq[h * 32 + d] * ks[h * 32 + d];
        Gk[bi * 16 + c] = redk[ci][0] + redk[ci][1] + redk[ci][2] + redk[ci][3];
        sbk[bi * 16 + c] = redb[ci][0] + redb[ci][1] + redb[ci][2] + redb[ci][3] + s * inv;
    }
}

// ==================== FUSED MAIN ==================== (round 14 + T5 setprio around MFMA clusters)
__global__ __launch_bounds__(512, 4) void fused_main_kernel(
    const float* __restrict__ img,
    const float* __restrict__ pbo, const float* __restrict__ pb2,
    const unsigned short* __restrict__ w1s, const unsigned short* __restrict__ w2s,
    const unsigned short* __restrict__ wks, const unsigned short* __restrict__ wvs,
    const float* __restrict__ Gk, const float* __restrict__ sbk,
    const float* __restrict__ B1,
    float* __restrict__ out)
{
    __shared__ __align__(16) char smem[81920];
    unsigned short* xsf = (unsigned short*)smem;            // [64*256] bf16, swz (r&31)<<3 (32K)
    // ring @ 32768: 8 waves x 4 slots x 1KB = 32K
    unsigned short* hsf = (unsigned short*)(smem + 65536);  // [64*128] bf16, swz (r&15)<<3 (16K)
    float* part_s  = (float*)(smem + 32768);                // [64*9]
    float* part_s2 = (float*)(smem + 35072);                // [64*9]
    unsigned short* alf = (unsigned short*)(smem + 32768);  // [64*32] (after parts dead)
    float* scf     = (float*)(smem + 37376);                // [2*64*16]
    float* outsf   = (float*)(smem + 32768);                // [64*128] f32 epilogue (ring dead)
    float* mean_s  = (float*)(smem + 65536);                // [64]
    float* rstd_s  = (float*)(smem + 65792);                // [64]

    const int t = threadIdx.x;
    const int lane = t & 63;
    const int wid = t >> 6;
    const int l15 = lane & 15;
    const int l4 = lane >> 4;
    const int bi = blockIdx.x >> 6;
    const int n0 = (blockIdx.x & 63) << 6;
    const int nc = wid * 32;
    unsigned short* wrg = (unsigned short*)(smem + 32768) + wid * 2048;  // 4 slots x 1KB, wave-private

    // ---- P0: transposed NT load, packed b128 LDS writes, fused LN1 partials
    {
        const float* imgb = img + ((size_t)bi * E) * NTOK + n0 + lane;
        float ps = 0.f, ps2 = 0.f;
        #pragma unroll
        for (int i = 0; i < 4; ++i) {
            int e0 = wid * 8 + i * 64;
            unsigned pk[4];
            #pragma unroll
            for (int jp = 0; jp < 4; ++jp) {
                float va = __builtin_nontemporal_load(&imgb[(size_t)(e0 + 2 * jp) * NTOK]);
                float vb = __builtin_nontemporal_load(&imgb[(size_t)(e0 + 2 * jp + 1) * NTOK]);
                unsigned short ha = f2bf(va), hb = f2bf(vb);
                float fa = bf2f(ha), fb = bf2f(hb);
                ps += fa + fb; ps2 += fa * fa + fb * fb;
                pk[jp] = (unsigned)ha | ((unsigned)hb << 16);
            }
            int idx = (lane * 256 + e0) ^ ((lane & 31) << 3);
            uint4 u = {pk[0], pk[1], pk[2], pk[3]};
            *(uint4*)&xsf[idx] = u;
        }
        part_s[lane * 9 + wid] = ps;
        part_s2[lane * 9 + wid] = ps2;
    }
    __syncthreads();

    if (t < 64) {
        float s = 0.f, s2 = 0.f;
        #pragma unroll
        for (int w = 0; w < 8; ++w) { s += part_s[t * 9 + w]; s2 += part_s2[t * 9 + w]; }
        float m = s * (1.f / 256.f);
        mean_s[t] = m;
        rstd_s[t] = rsqrtf(s2 * (1.f / 256.f) - m * m + 1e-5f);
    }

    // ---- P3a: score partials via MFMA, all 8 waves (split-K)
    {
        const int mt = wid >> 1, kh = wid & 1;
        f32x4 p = {0.f, 0.f, 0.f, 0.f};
        __builtin_amdgcn_s_setprio(1);
        #pragma unroll
        for (int kq = 0; kq < 4; ++kq) {
            int kk = kh * 4 + kq;
            int row = mt * 16 + l15;
            bf16x8 a = *(const bf16x8*)&xsf[(row * 256 + kk * 32 + l4 * 8) ^ ((row & 31) << 3)];
            bf16x8 bfr = *(const bf16x8*)&wks[(bi * 8 + kk) * 512 + lane * 8];
            p = __builtin_amdgcn_mfma_f32_16x16x32_bf16(a, bfr, p, 0, 0, 0);
        }
        __builtin_amdgcn_s_setprio(0);
        #pragma unroll
        for (int rg = 0; rg < 4; ++rg)
            scf[(kh * 64 + mt * 16 + l4 * 4 + rg) * 16 + l15] = p[rg];
    }
    __syncthreads();

    // ---- P3b: LN1-fold + softmax -> alf
    {
        int r = t >> 3, h = t & 7;
        float gk0 = Gk[bi * 16 + h], gk1 = Gk[bi * 16 + 8 + h];
        float sb0 = sbk[bi * 16 + h], sb1 = sbk[bi * 16 + 8 + h];
        float ms = mean_s[r], rs = rstd_s[r];
        float raw0 = scf[r * 16 + h] + scf[(64 + r) * 16 + h];
        float raw1 = scf[r * 16 + 8 + h] + scf[(64 + r) * 16 + 8 + h];
        float s0 = rs * (raw0 - ms * gk0) + sb0;
        float s1 = rs * (raw1 - ms * gk1) + sb1;
        float mx = fmaxf(s0, s1);
        float e0 = __expf(s0 - mx), e1 = __expf(s1 - mx);
        float is = __builtin_amdgcn_rcpf(e0 + e1);
        alf[r * 32 + h] = f2bf(e0 * is);
        alf[r * 32 + 8 + h] = f2bf(e1 * is);
        alf[r * 32 + 16 + h] = 0;
        alf[r * 32 + 24 + h] = 0;
    }
    __syncthreads();

    // ---- P3c: attended MFMA + residual; x1 -> xsf (bf16), acc2 seeded with x1 + b2
    f32x4 acc2[4][2];
    {
        f32x4 pa[4][2];
        #pragma unroll
        for (int m = 0; m < 4; ++m)
            #pragma unroll
            for (int n = 0; n < 2; ++n)
                pa[m][n] = f32x4{0.f, 0.f, 0.f, 0.f};
        bf16x8 bv[2];
        #pragma unroll
        for (int n = 0; n < 2; ++n)
            bv[n] = *(const bf16x8*)&wvs[(bi * 16 + wid * 2 + n) * 512 + lane * 8];
        __builtin_amdgcn_s_setprio(1);
        #pragma unroll
        for (int m = 0; m < 4; ++m) {
            bf16x8 af = *(const bf16x8*)&alf[(m * 16 + l15) * 32 + l4 * 8];
            #pragma unroll
            for (int n = 0; n < 2; ++n)
                pa[m][n] = __builtin_amdgcn_mfma_f32_16x16x32_bf16(af, bv[n], pa[m][n], 0, 0, 0);
        }
        __builtin_amdgcn_s_setprio(0);
        float bov[2], b2v[2];
        #pragma unroll
        for (int n = 0; n < 2; ++n) {
            bov[n] = pbo[nc + n * 16 + l15];
            b2v[n] = pb2[nc + n * 16 + l15];
        }
        #pragma unroll
        for (int m = 0; m < 4; ++m)
            #pragma unroll
            for (int n = 0; n < 2; ++n)
                #pragma unroll
                for (int rg = 0; rg < 4; ++rg) {
                    int R = m * 16 + l4 * 4 + rg;
                    int C = nc + n * 16 + l15;
                    int xi = (R * 256 + C) ^ ((R & 31) << 3);
                    float x1 = bf2f(xsf[xi]) + pa[m][n][rg] + bov[n];
                    xsf[xi] = f2bf(x1);
                    acc2[m][n][rg] = x1 + b2v[n];
                }
    }

    // preload per-chunk bias; retired by the sync below
    float b1pre[8];
    #pragma unroll
    for (int c = 0; c < 8; ++c)
        b1pre[c] = B1[c * 128 + wid * 16 + l15];
    __syncthreads();   // also drains vmcnt -> gll counting below starts from 0

    // ---- P4: LN2 stats
    for (int rr = 0; rr < 8; ++rr) {
        int r = wid * 8 + rr;
        int idx = (r * 256 + lane * 4) ^ ((r & 31) << 3);
        ushort4 xv = *(const ushort4*)&xsf[idx];
        float v0 = bf2f(xv.x), v1 = bf2f(xv.y), v2 = bf2f(xv.z), v3 = bf2f(xv.w);
        float s = v0 + v1 + v2 + v3;
        float s2 = v0 * v0 + v1 * v1 + v2 * v2 + v3 * v3;
        for (int off = 32; off; off >>= 1) { s += __shfl_down(s, off); s2 += __shfl_down(s2, off); }
        if (lane == 0) {
            float m = s * (1.f / 256.f);
            mean_s[r] = m;
            rstd_s[r] = rsqrtf(s2 * (1.f / 256.f) - m * m + 1e-5f);
        }
    }
    bar_lds();

    // ---- FFN: FC=128, 8 chunks x 16 frags; wave-private 4-slot gll ring, depth-3
    #define ISSUE(S) do { if ((S) <= 127) { \
        const int c_ = (S) >> 4, j_ = (S) & 15; \
        const unsigned short* src_; \
        if (j_ < 8) src_ = w1s + (size_t)((c_ * 64 + j_) * 512) + wid * 4096 + lane * 8; \
        else { const int kkl_ = (j_ - 8) >> 1, og_ = (j_ - 8) & 1; \
               src_ = w2s + (size_t)((((c_ >> 1) * 128 + og_ * 8 + (c_ & 1) * 4 + kkl_)) * 512) + wid * 8192 + lane * 8; } \
        gll16(src_, wrg + ((S) & 3) * 512); \
    } } while (0)

    // prologue: frags 0-2 in flight while we normalize xsf below
    ISSUE(0); ISSUE(1); ISSUE(2);

    // ---- Normalize pass: xsf <- bf16( (x1 - mean)*rstd )  (stats die here)
    {
        int r = t >> 3;
        int c0 = (t & 7) * 32;
        float mr = mean_s[r], rr2 = rstd_s[r];
        #pragma unroll
        for (int j = 0; j < 4; ++j) {
            int idx = (r * 256 + c0 + j * 8) ^ ((r & 31) << 3);
            uint4 u = *(const uint4*)&xsf[idx];
            unsigned pk[4] = {u.x, u.y, u.z, u.w};
            #pragma unroll
            for (int w = 0; w < 4; ++w) {
                float lo = bf2f((unsigned short)(pk[w] & 0xffffu));
                float hi = bf2f((unsigned short)(pk[w] >> 16));
                lo = (lo - mr) * rr2;
                hi = (hi - mr) * rr2;
                pk[w] = (unsigned)f2bf(lo) | ((unsigned)f2bf(hi) << 16);
            }
            uint4 o = {pk[0], pk[1], pk[2], pk[3]};
            *(uint4*)&xsf[idx] = o;
        }
    }
    bar_lds();

    #define G1STEP(S) { \
        const int kb_ = ((S) & 15) * 32 + l4 * 8; \
        bf16x8 x0_ = *(const bf16x8*)&xsf[((l15) * 256 + kb_) ^ (((l15) & 31) << 3)]; \
        bf16x8 x1_ = *(const bf16x8*)&xsf[((16 + l15) * 256 + kb_) ^ (((16 + l15) & 31) << 3)]; \
        bf16x8 x2_ = *(const bf16x8*)&xsf[((32 + l15) * 256 + kb_) ^ (((32 + l15) & 31) << 3)]; \
        bf16x8 x3_ = *(const bf16x8*)&xsf[((48 + l15) * 256 + kb_) ^ (((48 + l15) & 31) << 3)]; \
        WAITV(S); \
        bf16x8 bf_ = *(const bf16x8*)&wrg[((S) & 3) * 512 + lane * 8]; \
        __builtin_amdgcn_s_setprio(1); \
        p[0] = __builtin_amdgcn_mfma_f32_16x16x32_bf16(x0_, bf_, p[0], 0, 0, 0); \
        p[1] = __builtin_amdgcn_mfma_f32_16x16x32_bf16(x1_, bf_, p[1], 0, 0, 0); \
        p[2] = __builtin_amdgcn_mfma_f32_16x16x32_bf16(x2_, bf_, p[2], 0, 0, 0); \
        p[3] = __builtin_amdgcn_mfma_f32_16x16x32_bf16(x3_, bf_, p[3], 0, 0, 0); \
        __builtin_amdgcn_s_setprio(0); \
        ISSUE((S) + 3); \
    }

    #define G2STEP(S) { \
        if ((((S) & 15) & 1) == 0) { \
            const int cb_ = (((((S) & 15) - 8) >> 1)) * 32 + l4 * 8; \
            af2[0] = *(const bf16x8*)&hsf[((l15) * 128 + cb_) ^ ((l15) << 3)]; \
            af2[1] = *(const bf16x8*)&hsf[((16 + l15) * 128 + cb_) ^ ((l15) << 3)]; \
            af2[2] = *(const bf16x8*)&hsf[((32 + l15) * 128 + cb_) ^ ((l15) << 3)]; \
            af2[3] = *(const bf16x8*)&hsf[((48 + l15) * 128 + cb_) ^ ((l15) << 3)]; \
        } \
        WAITV(S); \
        bf16x8 bf_ = *(const bf16x8*)&wrg[((S) & 3) * 512 + lane * 8]; \
        __builtin_amdgcn_s_setprio(1); \
        { const int og_ = ((S) & 15) & 1; \
          acc2[0][og_] = __builtin_amdgcn_mfma_f32_16x16x32_bf16(af2[0], bf_, acc2[0][og_], 0, 0, 0); \
          acc2[1][og_] = __builtin_amdgcn_mfma_f32_16x16x32_bf16(af2[1], bf_, acc2[1][og_], 0, 0, 0); \
          acc2[2][og_] = __builtin_amdgcn_mfma_f32_16x16x32_bf16(af2[2], bf_, acc2[2][og_], 0, 0, 0); \
          acc2[3][og_] = __builtin_amdgcn_mfma_f32_16x16x32_bf16(af2[3], bf_, acc2[3][og_], 0, 0, 0); } \
        __builtin_amdgcn_s_setprio(0); \
        ISSUE((S) + 3); \
    }

    #define GELUC(C) { \
        const float b1v_ = b1pre[(C)]; \
        _Pragma("unroll") \
        for (int m_ = 0; m_ < 4; ++m_) { \
            _Pragma("unroll") \
            for (int rg_ = 0; rg_ < 4; ++rg_) { \
                int R_ = m_ * 16 + l4 * 4 + rg_; \
                float hp_ = p[m_][rg_] + b1v_; \
                hsf[(R_ * 128 + wid * 16 + l15) ^ ((R_ & 15) << 3)] = f2bf(gelu_fast(hp_)); \
            } \
            p[m_] = f32x4{0.f, 0.f, 0.f, 0.f}; \
        } \
    }

    #define CHUNK(C) { \
        G1STEP((C)*16 + 0); G1STEP((C)*16 + 1); G1STEP((C)*16 + 2); G1STEP((C)*16 + 3); \
        G1STEP((C)*16 + 4); G1STEP((C)*16 + 5); G1STEP((C)*16 + 6); G1STEP((C)*16 + 7); \
        GELUC(C); \
        bar_lds(); \
        G2STEP((C)*16 + 8);  G2STEP((C)*16 + 9);  G2STEP((C)*16 + 10); G2STEP((C)*16 + 11); \
        G2STEP((C)*16 + 12); G2STEP((C)*16 + 13); G2STEP((C)*16 + 14); G2STEP((C)*16 + 15); \
        bar_lds(); \
    }

    f32x4 p[4];
    #pragma unroll
    for (int m = 0; m < 4; ++m) p[m] = f32x4{0.f, 0.f, 0.f, 0.f};
    bf16x8 af2[4];

    CHUNK(0) CHUNK(1) CHUNK(2) CHUNK(3) CHUNK(4) CHUNK(5) CHUNK(6) CHUNK(7)

    #undef ISSUE
    #undef G1STEP
    #undef G2STEP
    #undef GELUC
    #undef CHUNK

    // ---- Epilogue: stage halves in LDS (ring region dead), vectorized NT stores
    #pragma unroll
    for (int h = 0; h < 2; ++h) {
        if ((wid >> 2) == h) {
            #pragma unroll
            for (int m = 0; m < 4; ++m)
                #pragma unroll
                for (int n = 0; n < 2; ++n)
                    #pragma unroll
                    for (int rg = 0; rg < 4; ++rg) {
                        int R = m * 16 + l4 * 4 + rg;
                        int Cl = nc + n * 16 + l15 - h * 128;
                        outsf[(R * 128 + Cl) ^ ((R & 7) << 2)] = acc2[m][n][rg];
                    }
        }
        __syncthreads();
        #pragma unroll
        for (int j = 0; j < 4; ++j) {
            int gidx = j * 512 + t;
            int e = gidx >> 4;
            int part = gidx & 15;
            f32x4 v;
            #pragma unroll
            for (int k2 = 0; k2 < 4; ++k2) {
                int nrow = part * 4 + k2;
                v[k2] = outsf[(nrow * 128 + e) ^ ((nrow & 7) << 2)];
            }
            __builtin_nontemporal_store(v,
                (f32x4*)(out + ((size_t)bi * E + h * 128 + e) * NTOK + n0 + part * 4));
        }
        if (h == 0) __syncthreads();
    }
}

extern "C" void kernel_launch(void* const* d_in, const int* in_sizes, int n_in,
                              void* d_out, int out_size, void* d_ws, size_t ws_size,
                              hipStream_t stream) {
    (void)in_sizes; (void)n_in; (void)out_size; (void)ws_size;
    const float* img   = (const float*)d_in[0];
    const float* tt    = (const float*)d_in[1];
    const float* bgt   = (const float*)d_in[2];
    const float* Wp    = (const float*)d_in[3];
    const float* bp    = (const float*)d_in[4];
    const float* g_img = (const float*)d_in[5];
    const float* b_img = (const float*)d_in[6];
    const float* g_tok = (const float*)d_in[7];
    const float* b_tok = (const float*)d_in[8];
    const float* g_ffn = (const float*)d_in[9];
    const float* b_ffn = (const float*)d_in[10];
    const float* Wq    = (const float*)d_in[11];
    const float* Wk    = (const float*)d_in[12];
    const float* Wv    = (const float*)d_in[13];
    const float* bq    = (const float*)d_in[14];
    const float* bk    = (const float*)d_in[15];
    const float* bv    = (const float*)d_in[16];
    const float* Wo    = (const float*)d_in[17];
    const float* bo    = (const float*)d_in[18];
    const float* W1    = (const float*)d_in[19];
    const float* b1    = (const float*)d_in[20];
    const float* W2    = (const float*)d_in[21];
    const float* b2    = (const float*)d_in[22];

    char* ws = (char*)d_ws;
    unsigned short* w1s = (unsigned short*)(ws);              // [0, 524288)
    unsigned short* w2s = (unsigned short*)(ws + 524288);     // [524288, 1048576)
    unsigned short* wks = (unsigned short*)(ws + 1048576);    // [1048576, 1179648)
    unsigned short* wvs = (unsigned short*)(ws + 1179648);    // [1179648, 1441792)
    float*          Gk  = (float*)(ws + 1441792);             // 1 KB
    float*          sbk = (float*)(ws + 1442816);             // 1 KB
    float*          G1  = (float*)(ws + 1443840);             // 4 KB (computed, unused by main)
    float*          B1  = (float*)(ws + 1447936);             // 4 KB

    hipLaunchKernelGGL(prep_kernel, dim3(288), dim3(256), 0, stream,
                       W1, W2, b1, tt, bgt, Wp, bp, g_tok, b_tok, g_img, b_img,
                       Wq, bq, Wk, bk, Wv, bv, Wo, g_ffn, b_ffn,
                       w1s, w2s, wks, wvs, Gk, sbk, G1, B1);
    hipLaunchKernelGGL(fused_main_kernel, dim3(1024), dim3(512), 0, stream,
                       img, bo, b2, w1s, w2s, wks, wvs, Gk, sbk, B1, (float*)d_out);
}